// Round 15
// baseline (129.463 us; speedup 1.0000x reference)
//
#include <hip/hip_runtime.h>
#include <hip/hip_bf16.h>

#define TROWS 1048576
#define RPC   256                    // rows per chunk
#define CPB   8                      // chunks per block
#define NBLK  (TROWS / (RPC * CPB))  // 512 blocks = 2 per CU
#define LSTRIDE 36                   // out0 LDS row stride in shorts (72 B)

typedef float f32x4  __attribute__((ext_vector_type(4)));
typedef short bf16x8 __attribute__((ext_vector_type(8)));
typedef short bf16x4 __attribute__((ext_vector_type(4)));

#define MFMA(a, b, c) __builtin_amdgcn_mfma_f32_16x16x32_bf16(a, b, c, 0, 0, 0)

__device__ __forceinline__ short f2bf(float v) {
    __hip_bfloat16 b = __float2bfloat16(v);
    return __builtin_bit_cast(short, b);
}
__device__ __forceinline__ float bf2f(short s) {
    unsigned u = ((unsigned)(unsigned short)s) << 16;
    return __builtin_bit_cast(float, u);
}

// k-map for ALL A/B fragments: kappa(g,j) = j<4 ? 4g+j : 16+4g+(j-4)
// ---------------------------------------------------------------------------
// Prep: weights -> bf16 fragment order (verified rounds 2-14).
//   W0a: frag 0..15 (ks*8+nt)   W0b: 16..23 (k2*2+ot)
//   W1a: 24..47 (ks*8+nt)       W1b: 48..55 (k2*2+ot)
// ---------------------------------------------------------------------------
__global__ __launch_bounds__(64) void prep_kernel(
    const float* __restrict__ W0a, const float* __restrict__ W0b,
    const float* __restrict__ W1a, const float* __restrict__ W1b,
    bf16x8* __restrict__ frag)
{
    const int fid = blockIdx.x, l = threadIdx.x, c = l & 15, g = l >> 4;
    const float* W; int N, ks, nt;
    if (fid < 16)      { W = W0a; N = 128; ks = fid >> 3;        nt = fid & 7; }
    else if (fid < 24) { W = W0b; N = 32;  ks = (fid - 16) >> 1; nt = (fid - 16) & 1; }
    else if (fid < 48) { W = W1a; N = 128; ks = (fid - 24) >> 3; nt = (fid - 24) & 7; }
    else               { W = W1b; N = 32;  ks = (fid - 48) >> 1; nt = (fid - 48) & 1; }
    bf16x8 f;
    #pragma unroll
    for (int j = 0; j < 8; ++j) {
        const int k = 32 * ks + ((j < 4) ? (4 * g + j) : (16 + 4 * g + (j - 4)));
        f[j] = f2bf(W[k * N + 16 * nt + c]);
    }
    frag[fid * 64 + l] = f;
}

// ---------------------------------------------------------------------------
// Persistent fused kernel, occupancy-first: 512 blocks x 512 threads (8 waves),
// 8 chunks x 256 rows each. All 56 weight frags LDS-resident for the whole
// block. Per wave: only 2 tiles -> ~100 VGPR -> 4 waves/SIMD with 2 blocks/CU
// = 16 waves/CU. No reg-prefetch (TLP hides chunk-top x loads).
// p-tile: prolog MLP0(x[p]) once (wave 7); per-chunk refresh = LDS reg-bounce
// of the chunk's cummax row across B_end (verified r14).
// ---------------------------------------------------------------------------
__global__ __launch_bounds__(512, 4) void fused_kernel(
    const float* __restrict__ x, const int* __restrict__ topk,
    const float* __restrict__ wts,
    const float* __restrict__ b0a, const float* __restrict__ b0b,
    const float* __restrict__ b1a, const float* __restrict__ b1b,
    const bf16x8* __restrict__ frag,
    float* __restrict__ out)
{
    const int tid = threadIdx.x, wv = tid >> 6, l = tid & 63, c = l & 15, g = l >> 4;
    const int rr = l & 31;             // scan row within wave's 32-row group
    const int blk0 = blockIdx.x * (RPC * CPB);

    __shared__ __align__(16) short frag_lds[56 * 64 * 8];    // 57344 B persistent
    __shared__ __align__(16) short out0_lds[257 * LSTRIDE];  // 18504 B
    __shared__ int wtot[8];

    #define LDSF(fid_) (*(const bf16x8*)&frag_lds[(((fid_) * 64) + l) * 8])

    // --- stage ALL 56 frags once: 3584 x 16B, 7 per thread ---
    #pragma unroll
    for (int i = 0; i < 7; ++i)
        *(f32x4*)&frag_lds[(tid + i * 512) * 8] = *(const f32x4*)&frag[tid + i * 512];

    // --- wave 7: initial p (last mask0 row < blk0) + x[p] -> bf16 frags ---
    bf16x8 xfp[2];
    bool m0p = false;
    if (wv == 7) {
        int p = 0;
        for (int base = blk0 - 64; base >= 0; base -= 64) {
            const int2 tkq = ((const int2*)topk)[base + l];
            const bool mm = (tkq.x == 0) || (tkq.y == 0);
            const unsigned long long bal = __ballot(mm);
            if (bal) { p = base + 63 - __clzll(bal); break; }
        }
        const int2 tkp = ((const int2*)topk)[p];
        m0p = (tkp.x == 0) || (tkp.y == 0);
        const float* xp = x + (size_t)p * 64;
        #pragma unroll
        for (int ks = 0; ks < 2; ++ks) {
            f32x4 a  = *(const f32x4*)(xp + 32 * ks + 4 * g);
            f32x4 b2 = *(const f32x4*)(xp + 32 * ks + 16 + 4 * g);
            #pragma unroll
            for (int j = 0; j < 4; ++j) { xfp[ks][j] = f2bf(a[j]); xfp[ks][4 + j] = f2bf(b2[j]); }
        }
    }

    __syncthreads();   // frags staged

    // --- wave 7: initial p-tile via MLP0 -> slot 256 (once per block).
    //     Happens-before every other wave's first gather (they wait at B_mid).
    if (wv == 7) {
        f32x4 accp0 = *(const f32x4*)(b0b + 4 * g);
        f32x4 accp1 = *(const f32x4*)(b0b + 16 + 4 * g);
        #pragma unroll 1
        for (int k2 = 0; k2 < 4; ++k2) {
            const bf16x8 fa00 = LDSF(0 * 8 + 2 * k2 + 0);
            const bf16x8 fa01 = LDSF(0 * 8 + 2 * k2 + 1);
            const bf16x8 fa10 = LDSF(1 * 8 + 2 * k2 + 0);
            const bf16x8 fa11 = LDSF(1 * 8 + 2 * k2 + 1);
            const bf16x8 fb0  = LDSF(16 + 2 * k2 + 0);
            const bf16x8 fb1  = LDSF(16 + 2 * k2 + 1);
            f32x4 a10 = *(const f32x4*)(b0a + 16 * (2 * k2 + 0) + 4 * g);
            f32x4 a11 = *(const f32x4*)(b0a + 16 * (2 * k2 + 1) + 4 * g);
            a10 = MFMA(fa00, xfp[0], a10);
            a10 = MFMA(fa10, xfp[1], a10);
            a11 = MFMA(fa01, xfp[0], a11);
            a11 = MFMA(fa11, xfp[1], a11);
            bf16x8 hf;
            #pragma unroll
            for (int j = 0; j < 8; ++j)
                hf[j] = f2bf(fmaxf((j < 4 ? a10 : a11)[j & 3], 0.0f));
            accp0 = MFMA(fb0, hf, accp0);
            accp1 = MFMA(fb1, hf, accp1);
        }
        if (c == 0) {
            #pragma unroll
            for (int ot = 0; ot < 2; ++ot) {
                bf16x4 v;
                #pragma unroll
                for (int j = 0; j < 4; ++j)
                    v[j] = f2bf(m0p ? (ot ? accp1[j] : accp0[j]) : 0.0f);
                *(bf16x4*)(&out0_lds[256 * LSTRIDE + 16 * ot + 4 * g]) = v;
            }
        }
    }

    #pragma unroll 1
    for (int ch = 0; ch < CPB; ++ch) {
        const int cb = blk0 + ch * RPC;

        // --- x load + convert: 2 tiles/wave (rows cb + wv*32 + rt*16 + c) ---
        bf16x8 xf[2][2];
        #pragma unroll
        for (int rt = 0; rt < 2; ++rt) {
            const float* xr = x + (size_t)(cb + wv * 32 + rt * 16 + c) * 64;
            #pragma unroll
            for (int ks = 0; ks < 2; ++ks) {
                f32x4 a  = *(const f32x4*)(xr + 32 * ks + 4 * g);
                f32x4 b2 = *(const f32x4*)(xr + 32 * ks + 16 + 4 * g);
                #pragma unroll
                for (int j = 0; j < 4; ++j) { xf[rt][ks][j] = f2bf(a[j]); xf[rt][ks][4 + j] = f2bf(b2[j]); }
            }
        }

        // --- scan: wave wv owns rows [cb+wv*32, +32); lanes 32-63 duplicate ---
        const int srow = cb + wv * 32 + rr;
        const int2 tko = ((const int2*)topk)[srow];
        const bool m0o = (tko.x == 0) || (tko.y == 0);
        int s = m0o ? srow : 0;
        #pragma unroll
        for (int off = 1; off < 32; off <<= 1) {
            int u = __shfl_up(s, off, 32);
            if (rr >= off) s = max(s, u);
        }
        if (l == 31) wtot[wv] = s;

        // ---- phase A: MLP0, rolled k2, frags from persistent LDS ----
        f32x4 acc2a[2][2];
        {
            f32x4 bi0 = *(const f32x4*)(b0b + 4 * g);
            f32x4 bi1 = *(const f32x4*)(b0b + 16 + 4 * g);
            acc2a[0][0] = bi0; acc2a[0][1] = bi1;
            acc2a[1][0] = bi0; acc2a[1][1] = bi1;
        }
        #pragma unroll 1
        for (int k2 = 0; k2 < 4; ++k2) {
            const bf16x8 fa00 = LDSF(0 * 8 + 2 * k2 + 0);
            const bf16x8 fa01 = LDSF(0 * 8 + 2 * k2 + 1);
            const bf16x8 fa10 = LDSF(1 * 8 + 2 * k2 + 0);
            const bf16x8 fa11 = LDSF(1 * 8 + 2 * k2 + 1);
            const bf16x8 fb0  = LDSF(16 + 2 * k2 + 0);
            const bf16x8 fb1  = LDSF(16 + 2 * k2 + 1);
            const f32x4 bi0 = *(const f32x4*)(b0a + 16 * (2 * k2 + 0) + 4 * g);
            const f32x4 bi1 = *(const f32x4*)(b0a + 16 * (2 * k2 + 1) + 4 * g);
            #pragma unroll
            for (int rt = 0; rt < 2; ++rt) {
                f32x4 a10 = bi0, a11 = bi1;
                a10 = MFMA(fa00, xf[rt][0], a10);
                a10 = MFMA(fa10, xf[rt][1], a10);
                a11 = MFMA(fa01, xf[rt][0], a11);
                a11 = MFMA(fa11, xf[rt][1], a11);
                bf16x8 hf;
                #pragma unroll
                for (int j = 0; j < 8; ++j)
                    hf[j] = f2bf(fmaxf((j < 4 ? a10 : a11)[j & 3], 0.0f));
                acc2a[rt][0] = MFMA(fb0, hf, acc2a[rt][0]);
                acc2a[rt][1] = MFMA(fb1, hf, acc2a[rt][1]);
            }
        }

        // --- store own tiles (masked, direct topk read) ---
        #pragma unroll
        for (int rt = 0; rt < 2; ++rt) {
            const int slot = wv * 32 + rt * 16 + c;
            const int2 tk = ((const int2*)topk)[cb + slot];
            const bool m0 = (tk.x == 0) || (tk.y == 0);
            #pragma unroll
            for (int ot = 0; ot < 2; ++ot) {
                bf16x4 v;
                #pragma unroll
                for (int j = 0; j < 4; ++j) v[j] = f2bf(m0 ? acc2a[rt][ot][j] : 0.0f);
                *(bf16x4*)(&out0_lds[slot * LSTRIDE + 16 * ot + 4 * g]) = v;
            }
        }

        __syncthreads();   // B_mid: out0 slots + wtot + slot 256 visible

        // --- chunk prefix -> global cummax per scan row ---
        int pre = 0;
        #pragma unroll
        for (int w2 = 0; w2 < 8; ++w2)
            if (w2 < wv) pre = max(pre, wtot[w2]);
        const int s_full = max(pre, s);

        // --- gather filled frags (slot 256 = p-tile when cummax < chunk base) ---
        bf16x8 xf2[2];
        #pragma unroll
        for (int rt = 0; rt < 2; ++rt) {
            const int sF = __shfl(s_full, rt * 16 + c, 64);
            const int slot = (sF >= cb) ? (sF - cb) : 256;
            const short* fr = &out0_lds[slot * LSTRIDE];
            bf16x4 fa_ = *(const bf16x4*)(fr + 4 * g);
            bf16x4 fb_ = *(const bf16x4*)(fr + 16 + 4 * g);
            #pragma unroll
            for (int j = 0; j < 4; ++j) { xf2[rt][j] = fa_[j]; xf2[rt][4 + j] = fb_[j]; }
        }

        // ---- phase B: MLP1, rolled k2 ----
        f32x4 acc2b[2][2];
        {
            f32x4 bi0 = *(const f32x4*)(b1b + 4 * g);
            f32x4 bi1 = *(const f32x4*)(b1b + 16 + 4 * g);
            acc2b[0][0] = bi0; acc2b[0][1] = bi1;
            acc2b[1][0] = bi0; acc2b[1][1] = bi1;
        }
        #pragma unroll 1
        for (int k2 = 0; k2 < 4; ++k2) {
            const bf16x8 fa00 = LDSF(24 + 0 * 8 + 2 * k2 + 0);
            const bf16x8 fa01 = LDSF(24 + 0 * 8 + 2 * k2 + 1);
            const bf16x8 fa10 = LDSF(24 + 1 * 8 + 2 * k2 + 0);
            const bf16x8 fa11 = LDSF(24 + 1 * 8 + 2 * k2 + 1);
            const bf16x8 fa20 = LDSF(24 + 2 * 8 + 2 * k2 + 0);
            const bf16x8 fa21 = LDSF(24 + 2 * 8 + 2 * k2 + 1);
            const bf16x8 fb0  = LDSF(48 + 2 * k2 + 0);
            const bf16x8 fb1  = LDSF(48 + 2 * k2 + 1);
            const f32x4 bi0 = *(const f32x4*)(b1a + 16 * (2 * k2 + 0) + 4 * g);
            const f32x4 bi1 = *(const f32x4*)(b1a + 16 * (2 * k2 + 1) + 4 * g);
            #pragma unroll
            for (int rt = 0; rt < 2; ++rt) {
                f32x4 a10 = bi0, a11 = bi1;
                a10 = MFMA(fa00, xf[rt][0], a10);
                a10 = MFMA(fa10, xf[rt][1], a10);
                a10 = MFMA(fa20, xf2[rt], a10);
                a11 = MFMA(fa01, xf[rt][0], a11);
                a11 = MFMA(fa11, xf[rt][1], a11);
                a11 = MFMA(fa21, xf2[rt], a11);
                bf16x8 hf;
                #pragma unroll
                for (int j = 0; j < 8; ++j)
                    hf[j] = f2bf(fmaxf((j < 4 ? a10 : a11)[j & 3], 0.0f));
                acc2b[rt][0] = MFMA(fb0, hf, acc2b[rt][0]);
                acc2b[rt][1] = MFMA(fb1, hf, acc2b[rt][1]);
            }
        }

        // --- blend + store (direct topk/wts reads) ---
        #pragma unroll
        for (int rt = 0; rt < 2; ++rt) {
            const int slot = wv * 32 + rt * 16 + c;
            const int row = cb + slot;
            const int2 tk = ((const int2*)topk)[row];
            const bool m1 = (tk.x == 1) || (tk.y == 1);
            const float w  = wts[(size_t)row * 2];
            const float wc = 1.0f - w;
            #pragma unroll
            for (int ot = 0; ot < 2; ++ot) {
                bf16x4 oa = *(const bf16x4*)(&out0_lds[slot * LSTRIDE + 16 * ot + 4 * g]);
                f32x4 r;
                #pragma unroll
                for (int j = 0; j < 4; ++j) {
                    const float e1 = m1 ? acc2b[rt][ot][j] : 0.0f;
                    r[j] = w * bf2f(oa[j]) + wc * e1;
                }
                *(f32x4*)(out + (size_t)row * 32 + 16 * ot + 4 * g) = r;
            }
        }

        // --- p-tile refresh: wave 7 bounces chunk cummax row through regs ---
        uint2 pc; bool docopy = false;
        if (ch + 1 < CPB && wv == 7) {
            const int pn = __shfl(s_full, 31, 64);   // cummax at row cb+255
            docopy = (pn >= cb);
            if (docopy && l < 8)
                pc = *(const uint2*)&out0_lds[(pn - cb) * LSTRIDE + l * 4];
        }

        __syncthreads();   // B_end: all out0 reads of this chunk done

        if (docopy && l < 8)
            *(uint2*)&out0_lds[256 * LSTRIDE + l * 4] = pc;
        // (visible to all at next B_mid; slots 0..255 stores are disjoint)
    }
    #undef LDSF
}

// ---------------------------------------------------------------------------
extern "C" void kernel_launch(void* const* d_in, const int* in_sizes, int n_in,
                              void* d_out, int out_size, void* d_ws, size_t ws_size,
                              hipStream_t stream)
{
    const float* x    = (const float*)d_in[0];
    const int*   topk = (const int*)  d_in[1];
    const float* wts  = (const float*)d_in[2];
    const float* W0a  = (const float*)d_in[3];
    const float* b0a  = (const float*)d_in[4];
    const float* W0b  = (const float*)d_in[5];
    const float* b0b  = (const float*)d_in[6];
    const float* W1a  = (const float*)d_in[7];
    const float* b1a  = (const float*)d_in[8];
    const float* W1b  = (const float*)d_in[9];
    const float* b1b  = (const float*)d_in[10];
    float* out = (float*)d_out;

    bf16x8* frag = (bf16x8*)d_ws;   // 56 KiB

    prep_kernel<<<dim3(56), dim3(64), 0, stream>>>(W0a, W0b, W1a, W1b, frag);
    fused_kernel<<<dim3(NBLK), dim3(512), 0, stream>>>(
        x, topk, wts, b0a, b0b, b1a, b1b, frag, out);
}